// Round 5
// baseline (3321.626 us; speedup 1.0000x reference)
//
#include <hip/hip_runtime.h>
#include <math.h>

// B=32, D=256, T=1024, H=512, 4H=2048
// Two independent groups of 16 blocks; group owns 16 batches, block owns 32 h-cols.
// Exchange: 64-bit relaxed agent atomics {bf16x2 data, step tag} -> LLC. No fences,
// no flags, no init (poisoned 0xAA never matches tags 1..1023).
// ws: [0,16MB) xT bf16 [T][B][D]; +16MB hbuf ull [2 phase][32 b][256 cp] (128 KB)

using short8  = __attribute__((ext_vector_type(8))) short;
using f32x4   = __attribute__((ext_vector_type(4))) float;
using float4v = __attribute__((ext_vector_type(4))) float;
using uint4v  = __attribute__((ext_vector_type(4))) unsigned;

__device__ inline unsigned short f2bf(float f) {
    unsigned u = __float_as_uint(f);
    unsigned r = u + 0x7fffu + ((u >> 16) & 1u);
    return (unsigned short)(r >> 16);
}
__device__ inline float fsig(float x) {
    return __builtin_amdgcn_rcpf(1.0f + __expf(-x));
}
__device__ inline float ftanh(float x) {
    return 2.0f * __builtin_amdgcn_rcpf(1.0f + __expf(-2.0f * x)) - 1.0f;
}

// ---------------- Phase 1: xT[t][b][d] = bf16(x[b][d][t]) ----------------
__global__ __launch_bounds__(256) void x_transpose(const float* __restrict__ x,
                                                   unsigned short* __restrict__ xT) {
    __shared__ unsigned short tile[64][65];
    const int tid = threadIdx.x;
    const int t0 = blockIdx.x * 64, d0 = blockIdx.y * 64, b = blockIdx.z;
    for (int p = 0; p < 16; p++) {
        int d = p * 4 + (tid >> 6);
        int t = tid & 63;
        tile[d][t] = f2bf(x[(b * 256 + d0 + d) * 1024 + t0 + t]);
    }
    __syncthreads();
    for (int p = 0; p < 16; p++) {
        int t = p * 4 + (tid >> 6);
        int d = tid & 63;
        xT[(size_t)(t0 + t) * 8192 + b * 256 + d0 + d] = tile[d][t];
    }
}

// ---------------- Phase 2: recurrence ----------------
#define HS 520   // h_lds row stride (shorts)
#define XS 264   // x_lds row stride (shorts)
#define GS 33    // gates_lds row stride (floats)
#define OS 17    // out_stage row stride (floats)

__global__ __launch_bounds__(512) void lstm_rec(const unsigned short* __restrict__ xT,
                                                const float* __restrict__ Wih,
                                                const float* __restrict__ Whh,
                                                const float* __restrict__ bih,
                                                const float* __restrict__ bhh,
                                                float* __restrict__ out,
                                                unsigned long long* hbuf) {
    __shared__ __align__(16) unsigned short h_lds[16 * HS];       // 16.6 KB
    __shared__ __align__(16) unsigned short x_lds[2][16 * XS];    // 16.9 KB
    __shared__ float gates_lds[4 * 16 * GS];                      // 8.4 KB
    __shared__ float out_stage[512 * OS];                         // 34.8 KB

    const int tid  = threadIdx.x;
    const int wave = tid >> 6;
    const int lane = tid & 63;
    const int quad = lane >> 4, l15 = lane & 15;
    const int group = blockIdx.x & 1;
    const int g     = blockIdx.x >> 1;         // h-slice [32g, 32g+32)
    const int gate  = wave >> 1;
    const int csub  = (wave & 1) * 16;

    const int nrow = gate * 512 + g * 32 + csub + l15;

    // one-time weight preload (frag layout: l15 = non-k dim, k = quad*8+j)
    short8 whh_frag[16];
    for (int ks = 0; ks < 16; ks++) {
        const float* p = &Whh[(size_t)nrow * 512 + ks * 32 + quad * 8];
        short8 v;
        for (int j = 0; j < 8; j++) v[j] = (short)f2bf(p[j]);
        whh_frag[ks] = v;
    }
    short8 wih_frag[8];
    for (int ks = 0; ks < 8; ks++) {
        const float* p = &Wih[(size_t)nrow * 256 + ks * 32 + quad * 8];
        short8 v;
        for (int j = 0; j < 8; j++) v[j] = (short)f2bf(p[j]);
        wih_frag[ks] = v;
    }
    const float bias_n = bih[nrow] + bhh[nrow];

    for (int i = tid; i < 16 * HS; i += 512) h_lds[i] = 0;
    {
        const unsigned short* src = xT + (size_t)(group * 16 + (tid >> 5)) * 256 + (tid & 31) * 8;
        *(short8*)&x_lds[0][(tid >> 5) * XS + (tid & 31) * 8] = *(const short8*)src;
    }

    const int eb = tid >> 5, ek = tid & 31;    // elementwise: local batch, local col
    const int hidx = g * 32 + ek;
    const bool self_cols = (ek >> 1) == g;     // this thread's reload range == own block's cols
    float c = 0.0f;
    float* out_base = out + ((size_t)(group * 16 + eb) * 512 + hidx) * 1024;
    unsigned long long* hb_row0 = hbuf + (size_t)(group * 16 + eb) * 256;  // + phase*32*256

    __syncthreads();

    // t=0 x-part
    f32x4 accA = f32x4{bias_n, bias_n, bias_n, bias_n};
    f32x4 accB = f32x4{0.f, 0.f, 0.f, 0.f};
    for (int ks = 0; ks < 8; ks += 2) {
        short8 a0 = *(const short8*)&x_lds[0][l15 * XS + ks * 32 + quad * 8];
        short8 a1 = *(const short8*)&x_lds[0][l15 * XS + (ks + 1) * 32 + quad * 8];
        accA = __builtin_amdgcn_mfma_f32_16x16x32_bf16(a0, wih_frag[ks], accA, 0, 0, 0);
        accB = __builtin_amdgcn_mfma_f32_16x16x32_bf16(a1, wih_frag[ks + 1], accB, 0, 0, 0);
    }

    for (int t = 0; t < 1024; t++) {
        // ---- h-part MFMAs (h_{t-1} in h_lds) ----
        for (int ks = 0; ks < 16; ks += 2) {
            short8 a0 = *(const short8*)&h_lds[l15 * HS + ks * 32 + quad * 8];
            short8 a1 = *(const short8*)&h_lds[l15 * HS + (ks + 1) * 32 + quad * 8];
            accA = __builtin_amdgcn_mfma_f32_16x16x32_bf16(a0, whh_frag[ks], accA, 0, 0, 0);
            accB = __builtin_amdgcn_mfma_f32_16x16x32_bf16(a1, whh_frag[ks + 1], accB, 0, 0, 0);
        }
        for (int r = 0; r < 4; r++) {
            int b = quad * 4 + r;
            gates_lds[(gate * 16 + b) * GS + csub + l15] = accA[r] + accB[r];
        }

        // prefetch x_{t+1}
        if (t + 1 < 1024) {
            const unsigned short* src = xT + (size_t)(t + 1) * 8192 +
                                        (size_t)(group * 16 + eb) * 256 + ek * 8;
            *(short8*)&x_lds[(t + 1) & 1][eb * XS + ek * 8] = *(const short8*)src;
        }
        __syncthreads();   // gates ready; h_lds reads for step t all done

        // ---- elementwise ----
        float iv = gates_lds[(0 * 16 + eb) * GS + ek];
        float fv = gates_lds[(1 * 16 + eb) * GS + ek];
        float gv = gates_lds[(2 * 16 + eb) * GS + ek];
        float ov = gates_lds[(3 * 16 + eb) * GS + ek];
        iv = fsig(iv); fv = fsig(fv); gv = ftanh(gv); ov = fsig(ov);
        c = fv * c + iv * gv;
        float h = ov * ftanh(c);

        out_stage[tid * OS + (t & 15)] = h;

        // own column straight into h_lds for step t+1 (safe: post-sync, disjoint region)
        unsigned my = f2bf(h);
        h_lds[eb * HS + hidx] = (unsigned short)my;

        // publish {bf16x2, tag} as one 64-bit atomic (fire-and-forget, no fence)
        unsigned nb = (unsigned)__shfl_xor((int)my, 1);
        if (t < 1023 && !(ek & 1)) {
            unsigned long long v = ((unsigned long long)(unsigned)(t + 1) << 32) |
                                   (unsigned long long)(my | (nb << 16));
            __hip_atomic_store(&hb_row0[(size_t)(t & 1) * 8192 + g * 16 + (ek >> 1)], v,
                               __ATOMIC_RELAXED, __HIP_MEMORY_SCOPE_AGENT);
        }

        // out flush every 16 steps (own LDS row — no sync needed)
        if ((t & 15) == 15) {
            int t0 = t & ~15;
            for (int q = 0; q < 4; q++) {
                float4v v = *(const float4v*)&out_stage[tid * OS + q * 4];
                *(float4v*)&out_base[t0 + q * 4] = v;
            }
        }

        if (t == 1023) break;

        // ---- next step's x-part while remote h lands ----
        accA = f32x4{bias_n, bias_n, bias_n, bias_n};
        accB = f32x4{0.f, 0.f, 0.f, 0.f};
        {
            const unsigned short* xb = x_lds[(t + 1) & 1];
            for (int ks = 0; ks < 8; ks += 2) {
                short8 a0 = *(const short8*)&xb[l15 * XS + ks * 32 + quad * 8];
                short8 a1 = *(const short8*)&xb[l15 * XS + (ks + 1) * 32 + quad * 8];
                accA = __builtin_amdgcn_mfma_f32_16x16x32_bf16(a0, wih_frag[ks], accA, 0, 0, 0);
                accB = __builtin_amdgcn_mfma_f32_16x16x32_bf16(a1, wih_frag[ks + 1], accB, 0, 0, 0);
            }
        }

        // ---- poll remote h_t directly (tag == t+1), write to h_lds ----
        if (!self_cols) {
            const unsigned long long* src = hb_row0 + (size_t)(t & 1) * 8192 + ek * 8;
            unsigned long long v[8];
            for (int j = 0; j < 8; j++)
                v[j] = __hip_atomic_load(src + j, __ATOMIC_RELAXED, __HIP_MEMORY_SCOPE_AGENT);
            const unsigned want = (unsigned)(t + 1);
            bool again = true;
            while (again) {
                again = false;
                for (int j = 0; j < 8; j++) {
                    if ((unsigned)(v[j] >> 32) != want) {
                        v[j] = __hip_atomic_load(src + j, __ATOMIC_RELAXED, __HIP_MEMORY_SCOPE_AGENT);
                        again = true;
                    }
                }
            }
            uint4v* dst = (uint4v*)&h_lds[eb * HS + ek * 16];
            dst[0] = uint4v{(unsigned)v[0], (unsigned)v[1], (unsigned)v[2], (unsigned)v[3]};
            dst[1] = uint4v{(unsigned)v[4], (unsigned)v[5], (unsigned)v[6], (unsigned)v[7]};
        }
        __syncthreads();
    }
}

extern "C" void kernel_launch(void* const* d_in, const int* in_sizes, int n_in,
                              void* d_out, int out_size, void* d_ws, size_t ws_size,
                              hipStream_t stream) {
    (void)in_sizes; (void)n_in; (void)out_size; (void)ws_size;
    const float* x   = (const float*)d_in[0];
    const float* Wih = (const float*)d_in[1];
    const float* Whh = (const float*)d_in[2];
    const float* bih = (const float*)d_in[3];
    const float* bhh = (const float*)d_in[4];
    float* out = (float*)d_out;

    char* ws = (char*)d_ws;
    unsigned short* xT      = (unsigned short*)ws;                 // 16,777,216 B
    unsigned long long* hbuf = (unsigned long long*)(ws + 16777216); // 128 KB

    dim3 gT(16, 4, 32);
    x_transpose<<<gT, 256, 0, stream>>>(x, xT);
    lstm_rec<<<32, 512, 0, stream>>>(xT, Wih, Whh, bih, bhh, out, hbuf);
}

// Round 6
// 3056.113 us; speedup vs baseline: 1.0869x; 1.0869x over previous
//
#include <hip/hip_runtime.h>
#include <math.h>

// B=32, D=256, T=1024, H=512, 4H=2048
// Two independent groups of 16 blocks; group owns 16 batches, block owns 32 h-cols.
// Wave layout: wave = (gate, khalf). Each wave: half of K, both 16-col tiles.
// Exchange: publish dword atomics -> s_waitcnt -> flag; poll flags; bulk load.
// LDS: XOR-granule swizzle (16B granule ^ (row&7)), no padding.
// ws: [0,16MB) xT bf16 [T][B][D]; +16MB flags (8KB); then hbuf dw [2grp][2ph][16][256]

using short8  = __attribute__((ext_vector_type(8))) short;
using f32x4   = __attribute__((ext_vector_type(4))) float;
using float4v = __attribute__((ext_vector_type(4))) float;
using uint4v  = __attribute__((ext_vector_type(4))) unsigned;

__device__ inline unsigned short f2bf(float f) {
    unsigned u = __float_as_uint(f);
    unsigned r = u + 0x7fffu + ((u >> 16) & 1u);
    return (unsigned short)(r >> 16);
}
__device__ inline float fsig(float x) {
    return __builtin_amdgcn_rcpf(1.0f + __expf(-x));
}
__device__ inline float ftanh(float x) {
    return 2.0f * __builtin_amdgcn_rcpf(1.0f + __expf(-2.0f * x)) - 1.0f;
}

__global__ void zero_flags(unsigned* p) {
    p[blockIdx.x * 256 + threadIdx.x] = 0u;
}

// ---------------- Phase 1: xT[t][b][d] = bf16(x[b][d][t]) ----------------
__global__ __launch_bounds__(256) void x_transpose(const float* __restrict__ x,
                                                   unsigned short* __restrict__ xT) {
    __shared__ unsigned short tile[64][65];
    const int tid = threadIdx.x;
    const int t0 = blockIdx.x * 64, d0 = blockIdx.y * 64, b = blockIdx.z;
    for (int p = 0; p < 16; p++) {
        int d = p * 4 + (tid >> 6);
        int t = tid & 63;
        tile[d][t] = f2bf(x[(b * 256 + d0 + d) * 1024 + t0 + t]);
    }
    __syncthreads();
    for (int p = 0; p < 16; p++) {
        int t = p * 4 + (tid >> 6);
        int d = tid & 63;
        xT[(size_t)(t0 + t) * 8192 + b * 256 + d0 + d] = tile[d][t];
    }
}

// ---------------- Phase 2: recurrence ----------------
#define GS 33    // gates_lds row stride (floats)
#define OS 17    // out_stage row stride (floats)

__global__ __launch_bounds__(512) void lstm_rec(const unsigned short* __restrict__ xT,
                                                const float* __restrict__ Wih,
                                                const float* __restrict__ Whh,
                                                const float* __restrict__ bih,
                                                const float* __restrict__ bhh,
                                                float* __restrict__ out,
                                                unsigned* flags,
                                                unsigned* hbuf) {
    __shared__ __align__(16) unsigned short h_lds[16 * 512];      // 16 KB, swizzled
    __shared__ __align__(16) unsigned short x_lds[2][16 * 256];   // 16 KB, swizzled
    __shared__ float gates_lds[8 * 16 * GS];                      // 16.9 KB (2 partials)
    __shared__ float out_stage[512 * OS];                         // 34.8 KB

    const int tid  = threadIdx.x;
    const int wave = tid >> 6;
    const int lane = tid & 63;
    const int quad = lane >> 4, l15 = lane & 15;
    const int l7   = l15 & 7;
    const int group = blockIdx.x & 1;
    const int g     = blockIdx.x >> 1;         // h-slice [32g, 32g+32)
    const int gate  = wave >> 1;               // i,f,g,o
    const int kh    = wave & 1;                // K-half

    // one-time weight preload: 2 col-tiles x (8 h-ks + 4 x-ks), K-range = kh half
    short8 whh_frag[2][8];
    short8 wih_frag[2][4];
    float bias_t[2];
    for (int tile = 0; tile < 2; tile++) {
        const int nrow = gate * 512 + g * 32 + tile * 16 + l15;
        for (int ks = 0; ks < 8; ks++) {
            const float* p = &Whh[(size_t)nrow * 512 + kh * 256 + ks * 32 + quad * 8];
            short8 v;
            for (int j = 0; j < 8; j++) v[j] = (short)f2bf(p[j]);
            whh_frag[tile][ks] = v;
        }
        for (int ks = 0; ks < 4; ks++) {
            const float* p = &Wih[(size_t)nrow * 256 + kh * 128 + ks * 32 + quad * 8];
            short8 v;
            for (int j = 0; j < 8; j++) v[j] = (short)f2bf(p[j]);
            wih_frag[tile][ks] = v;
        }
        bias_t[tile] = (kh == 0) ? (bih[nrow] + bhh[nrow]) : 0.0f;
    }

    const int eb = tid >> 5, ek = tid & 31;    // elementwise: local batch, local col
    const int e7 = eb & 7;
    const int hidx = g * 32 + ek;

    for (int i = tid; i < 16 * 512; i += 512) h_lds[i] = 0;
    {   // stage x_lds[0] (swizzled granule = ek ^ e7)
        const unsigned short* src = xT + (size_t)(group * 16 + eb) * 256 + ek * 8;
        *(short8*)&x_lds[0][eb * 256 + (ek ^ e7) * 8] = *(const short8*)src;
    }

    float c = 0.0f;
    float* out_base = out + ((size_t)(group * 16 + eb) * 512 + hidx) * 1024;
    unsigned* my_flags = flags + group * 512;            // 16 flags, 128 B apart
    unsigned* hb_base  = hbuf + group * 8192;            // [2 phase][16 b][256 cp]

    __syncthreads();

    // t=0 x-part
    f32x4 acc0 = f32x4{bias_t[0], bias_t[0], bias_t[0], bias_t[0]};
    f32x4 acc1 = f32x4{bias_t[1], bias_t[1], bias_t[1], bias_t[1]};
    for (int ks = 0; ks < 4; ks++) {
        short8 af = *(const short8*)&x_lds[0][l15 * 256 + (((kh << 4) + (ks << 2) + quad) ^ l7) * 8];
        acc0 = __builtin_amdgcn_mfma_f32_16x16x32_bf16(af, wih_frag[0][ks], acc0, 0, 0, 0);
        acc1 = __builtin_amdgcn_mfma_f32_16x16x32_bf16(af, wih_frag[1][ks], acc1, 0, 0, 0);
    }

    for (int t = 0; t < 1024; t++) {
        // ---- h-part: 8 A-reads feed 16 MFMAs (2 col-tiles) ----
        for (int ks = 0; ks < 8; ks++) {
            short8 af = *(const short8*)&h_lds[l15 * 512 + (((kh << 5) + (ks << 2) + quad) ^ l7) * 8];
            acc0 = __builtin_amdgcn_mfma_f32_16x16x32_bf16(af, whh_frag[0][ks], acc0, 0, 0, 0);
            acc1 = __builtin_amdgcn_mfma_f32_16x16x32_bf16(af, whh_frag[1][ks], acc1, 0, 0, 0);
        }
        {
            const int prow = (kh * 4 + gate) * 16;
            for (int r = 0; r < 4; r++) {
                gates_lds[(prow + quad * 4 + r) * GS + l15]      = acc0[r];
                gates_lds[(prow + quad * 4 + r) * GS + 16 + l15] = acc1[r];
            }
        }

        // prefetch x_{t+1} into the other swizzled buffer
        if (t + 1 < 1024) {
            const unsigned short* src = xT + (size_t)(t + 1) * 8192 +
                                        (size_t)(group * 16 + eb) * 256 + ek * 8;
            *(short8*)&x_lds[(t + 1) & 1][eb * 256 + (ek ^ e7) * 8] = *(const short8*)src;
        }
        __syncthreads();   // gates partials ready; all h_lds reads for step t done

        // ---- elementwise: sum K-half partials, gate math ----
        float iv = gates_lds[(0 * 16 + eb) * GS + ek] + gates_lds[(4 * 16 + eb) * GS + ek];
        float fv = gates_lds[(1 * 16 + eb) * GS + ek] + gates_lds[(5 * 16 + eb) * GS + ek];
        float gv = gates_lds[(2 * 16 + eb) * GS + ek] + gates_lds[(6 * 16 + eb) * GS + ek];
        float ov = gates_lds[(3 * 16 + eb) * GS + ek] + gates_lds[(7 * 16 + eb) * GS + ek];
        iv = fsig(iv); fv = fsig(fv); gv = ftanh(gv); ov = fsig(ov);
        c = fv * c + iv * gv;
        float h = ov * ftanh(c);

        out_stage[tid * OS + (t & 15)] = h;

        // own column straight into h_lds (post-sync, disjoint from other writers)
        unsigned my = f2bf(h);
        {
            int phys = (g * 4 + (ek >> 3)) ^ e7;
            h_lds[eb * 512 + phys * 8 + (ek & 7)] = (unsigned short)my;
        }

        // publish packed bf16x2 dwords (fire now, drain later)
        unsigned nb = (unsigned)__shfl_xor((int)my, 1);
        if (t < 1023 && !(ek & 1)) {
            __hip_atomic_store(&hb_base[(t & 1) * 4096 + eb * 256 + g * 16 + (ek >> 1)],
                               my | (nb << 16), __ATOMIC_RELAXED, __HIP_MEMORY_SCOPE_AGENT);
        }

        // out flush every 16 steps (own LDS row — no sync needed)
        if ((t & 15) == 15) {
            int t0 = t & ~15;
            for (int q = 0; q < 4; q++) {
                float4v v = *(const float4v*)&out_stage[tid * OS + q * 4];
                *(float4v*)&out_base[t0 + q * 4] = v;
            }
        }

        if (t == 1023) break;

        // ---- next step's x-part while publish stores drain ----
        acc0 = f32x4{bias_t[0], bias_t[0], bias_t[0], bias_t[0]};
        acc1 = f32x4{bias_t[1], bias_t[1], bias_t[1], bias_t[1]};
        {
            const unsigned short* xb = x_lds[(t + 1) & 1];
            for (int ks = 0; ks < 4; ks++) {
                short8 af = *(const short8*)&xb[l15 * 256 + (((kh << 4) + (ks << 2) + quad) ^ l7) * 8];
                acc0 = __builtin_amdgcn_mfma_f32_16x16x32_bf16(af, wih_frag[0][ks], acc0, 0, 0, 0);
                acc1 = __builtin_amdgcn_mfma_f32_16x16x32_bf16(af, wih_frag[1][ks], acc1, 0, 0, 0);
            }
        }

        // ---- drain own stores, then flag ----
        __builtin_amdgcn_s_waitcnt(0);
        __syncthreads();
        if (tid == 0)
            __hip_atomic_store(&my_flags[g * 32], (unsigned)(t + 1),
                               __ATOMIC_RELAXED, __HIP_MEMORY_SCOPE_AGENT);

        // ---- wait for all 16 producers ----
        if (wave == 0 && lane < 16) {
            while (__hip_atomic_load(&my_flags[lane * 32], __ATOMIC_RELAXED,
                                     __HIP_MEMORY_SCOPE_AGENT) <= (unsigned)t) { }
        }
        __syncthreads();

        // ---- bulk-load remote h_t (32 B/thread), write swizzled to h_lds ----
        if ((ek >> 1) != g) {
            const unsigned long long* src =
                (const unsigned long long*)&hb_base[(t & 1) * 4096 + eb * 256 + ek * 8];
            unsigned long long v0 = __hip_atomic_load(src + 0, __ATOMIC_RELAXED, __HIP_MEMORY_SCOPE_AGENT);
            unsigned long long v1 = __hip_atomic_load(src + 1, __ATOMIC_RELAXED, __HIP_MEMORY_SCOPE_AGENT);
            unsigned long long v2 = __hip_atomic_load(src + 2, __ATOMIC_RELAXED, __HIP_MEMORY_SCOPE_AGENT);
            unsigned long long v3 = __hip_atomic_load(src + 3, __ATOMIC_RELAXED, __HIP_MEMORY_SCOPE_AGENT);
            int pa = (2 * ek) ^ e7;
            int pb = (2 * ek + 1) ^ e7;
            *(uint4v*)&h_lds[eb * 512 + pa * 8] =
                uint4v{(unsigned)v0, (unsigned)(v0 >> 32), (unsigned)v1, (unsigned)(v1 >> 32)};
            *(uint4v*)&h_lds[eb * 512 + pb * 8] =
                uint4v{(unsigned)v2, (unsigned)(v2 >> 32), (unsigned)v3, (unsigned)(v3 >> 32)};
        }
        __syncthreads();
    }
}

extern "C" void kernel_launch(void* const* d_in, const int* in_sizes, int n_in,
                              void* d_out, int out_size, void* d_ws, size_t ws_size,
                              hipStream_t stream) {
    (void)in_sizes; (void)n_in; (void)out_size; (void)ws_size;
    const float* x   = (const float*)d_in[0];
    const float* Wih = (const float*)d_in[1];
    const float* Whh = (const float*)d_in[2];
    const float* bih = (const float*)d_in[3];
    const float* bhh = (const float*)d_in[4];
    float* out = (float*)d_out;

    char* ws = (char*)d_ws;
    unsigned short* xT = (unsigned short*)ws;                 // 16,777,216 B
    unsigned* flags    = (unsigned*)(ws + 16777216);          // 8 KB
    unsigned* hbuf     = (unsigned*)(ws + 16777216 + 8192);   // 64 KB

    zero_flags<<<8, 256, 0, stream>>>(flags);
    dim3 gT(16, 4, 32);
    x_transpose<<<gT, 256, 0, stream>>>(x, xT);
    lstm_rec<<<32, 512, 0, stream>>>(xT, Wih, Whh, bih, bhh, out, flags, hbuf);
}